// Round 11
// baseline (209.453 us; speedup 1.0000x reference)
//
#include <hip/hip_runtime.h>

#define N_NODES 512
#define INNER   256
#define IN_DIM  128
#define EDGE_DIM 64
#define NH 8
#define HD 32
#define SCALE 0.17677669529663687f  // 1/sqrt(32)

// ---------------------------------------------------------------------------
// K0: q/k/v projections. Block (m, i-tile of 8). 192 blocks x 256 thr.
// ---------------------------------------------------------------------------
__global__ __launch_bounds__(256) void proj_qkv(
    const float* __restrict__ nodes,
    const float* __restrict__ Wq, const float* __restrict__ bq,
    const float* __restrict__ Wk, const float* __restrict__ bk,
    const float* __restrict__ Wv, const float* __restrict__ bv,
    float* __restrict__ q, float* __restrict__ k, float* __restrict__ v) {
  const int m  = blockIdx.x >> 6;
  const int i0 = (blockIdx.x & 63) * 8;
  const int n  = threadIdx.x;
  const float* __restrict__ W = (m == 0) ? Wq : (m == 1) ? Wk : Wv;
  const float* __restrict__ b = (m == 0) ? bq : (m == 1) ? bk : bv;
  float*       __restrict__ o = (m == 0) ? q  : (m == 1) ? k  : v;

  __shared__ float s_n[8 * IN_DIM];
  *(float4*)&s_n[n * 4] = *(const float4*)&nodes[(size_t)i0 * IN_DIM + n * 4];
  __syncthreads();

  float acc[8] = {0.f, 0.f, 0.f, 0.f, 0.f, 0.f, 0.f, 0.f};
#pragma unroll 4
  for (int c = 0; c < IN_DIM; ++c) {
    const float w = W[(size_t)c * INNER + n];
#pragma unroll
    for (int r = 0; r < 8; ++r) acc[r] = fmaf(s_n[r * IN_DIM + c], w, acc[r]);
  }
  const float bn = b[n];
#pragma unroll
  for (int r = 0; r < 8; ++r) o[(size_t)(i0 + r) * INNER + n] = acc[r] + bn;
}

// ---------------------------------------------------------------------------
// K0b: qe[i,h,c] = q_ih . We[c, h*32..]; qb[i,h] = q_ih . be_h.
// ---------------------------------------------------------------------------
__global__ __launch_bounds__(512) void qe_qb(
    const float* __restrict__ q, const float* __restrict__ We,
    const float* __restrict__ be,
    float* __restrict__ qe, float* __restrict__ qb) {
  const int i0  = blockIdx.x * 8;
  const int tid = threadIdx.x;

  __shared__ float s_q[8 * INNER];
  *(float4*)&s_q[tid * 4] = *(const float4*)&q[(size_t)i0 * INNER + tid * 4];
  __syncthreads();

  const int h = tid >> 6, c = tid & 63;
  float4 w[8];
#pragma unroll
  for (int d4 = 0; d4 < 8; ++d4)
    w[d4] = *(const float4*)&We[(size_t)c * INNER + h * HD + d4 * 4];

#pragma unroll
  for (int il = 0; il < 8; ++il) {
    const float* qh = &s_q[il * INNER + h * HD];
    float acc = 0.f;
#pragma unroll
    for (int d4 = 0; d4 < 8; ++d4) {
      const float4 q4 = *(const float4*)&qh[d4 * 4];
      acc += q4.x * w[d4].x + q4.y * w[d4].y + q4.z * w[d4].z + q4.w * w[d4].w;
    }
    qe[(size_t)(i0 + il) * (NH * EDGE_DIM) + h * EDGE_DIM + c] = acc;
  }

  if (tid < 64) {
    const int il = tid >> 3, h2 = tid & 7;
    float acc = 0.f;
    for (int d = 0; d < HD; ++d)
      acc += s_q[il * INNER + h2 * HD + d] * be[h2 * HD + d];
    qb[(size_t)(i0 + il) * NH + h2] = acc;
  }
}

// ---------------------------------------------------------------------------
// K1: qk[i,h,j] = q_ih . k_jh (unscaled). 16x16 tile, LDS-staged, coalesced.
// ---------------------------------------------------------------------------
__global__ __launch_bounds__(256) void qk_gemm(
    const float* __restrict__ q, const float* __restrict__ k,
    float* __restrict__ qk) {
  const int it = blockIdx.x >> 5, jt = blockIdx.x & 31;
  const int i0 = it * 16, j0 = jt * 16;
  const int tid = threadIdx.x;

  __shared__ float sq[16 * 260];
  __shared__ float sk[16 * 260];
#pragma unroll
  for (int p = 0; p < 4; ++p) {
    const int s = tid + p * 256;
    const int row = s >> 6, c4 = s & 63;
    *(float4*)&sq[row * 260 + c4 * 4] =
        *(const float4*)&q[(size_t)(i0 + row) * INNER + c4 * 4];
    *(float4*)&sk[row * 260 + c4 * 4] =
        *(const float4*)&k[(size_t)(j0 + row) * INNER + c4 * 4];
  }
  __syncthreads();

  const int il = tid >> 4, jl = tid & 15;
  float acc[NH];
#pragma unroll
  for (int h = 0; h < NH; ++h) {
    float s = 0.f;
#pragma unroll
    for (int d4 = 0; d4 < 8; ++d4) {
      const float4 q4 = *(const float4*)&sq[il * 260 + h * HD + d4 * 4];
      const float4 k4 = *(const float4*)&sk[jl * 260 + h * HD + d4 * 4];
      s += q4.x * k4.x + q4.y * k4.y + q4.z * k4.z + q4.w * k4.w;
    }
    acc[h] = s;
  }
#pragma unroll
  for (int h = 0; h < NH; ++h)
    qk[(size_t)(i0 + il) * (NH * N_NODES) + h * N_NODES + j0 + jl] = acc[h];
}

// ---------------------------------------------------------------------------
// K2: single-pass fused attention. Phase B consumes the STAGED REGISTERS
// (rows {rS, rS+32, rS+64, rS+96} x col-group cgS live in e0..e3) -> zero
// e-LDS reads in B, killing the 8x head re-read amplification (round-9
// LDS-BW bound). p reads are 16-lane broadcasts (free). ae partials reduced
// via shfl_xor and published into the e_tile region (reused after last chunk).
// ---------------------------------------------------------------------------
__global__ __launch_bounds__(512, 4) void fused_attn(
    const float* __restrict__ edges, const int* __restrict__ adjacency,
    const float* __restrict__ v,
    const float* __restrict__ qe, const float* __restrict__ qb,
    const float* __restrict__ qkbuf,
    const float* __restrict__ We, const float* __restrict__ be,
    float* __restrict__ out) {
  const int i   = blockIdx.x;
  const int tid = threadIdx.x;

  // u_tile: [128][68] e-tile during chunks; after last chunk reused as
  // aep[8][512] (ae wave-partials, floats 0..4095) + ae[512] (4096..4607).
  __shared__ float u_tile[128 * 68];
  __shared__ float p_lds[NH * 128];
  __shared__ float s_qe[NH * EDGE_DIM];
  __shared__ float s_qb[NH];
  __shared__ float s_adj[N_NODES];
  __shared__ float s_hred[8][2];
  __shared__ float s_rd[NH];
  __shared__ float s_as[NH];
  __shared__ float s_avp[2][INNER];

  s_qe[tid]  = qe[(size_t)i * (NH * EDGE_DIM) + tid];
  s_adj[tid] = (float)adjacency[(size_t)i * N_NODES + tid];
  if (tid < NH) s_qb[tid] = qb[(size_t)i * NH + tid];

  const int rS  = tid >> 4,  cgS = tid & 15;               // stage + B role
  const int j_l = tid & 127, hg = tid >> 7, h0 = hg * 2;   // phase A role
  const int nC  = tid & 255, p2 = tid >> 8, hv = nC >> 5;  // phase C role

  float hs0 = 0.f, hs1 = 0.f, accv = 0.f;
  float4 acc4[NH];
#pragma unroll
  for (int h = 0; h < NH; ++h) acc4[h] = make_float4(0.f, 0.f, 0.f, 0.f);

  const float* ebase = edges + (size_t)i * (N_NODES * EDGE_DIM);

  for (int jc = 0; jc < 4; ++jc) {
    // ---- load this chunk's 4 float4 (rows rS+32p, col-group cgS) ----
    const float* esrc = ebase + (size_t)jc * (128 * EDGE_DIM);
    const float4 e0 = *(const float4*)&esrc[(size_t)(tid +    0) * 4];
    const float4 e1 = *(const float4*)&esrc[(size_t)(tid +  512) * 4];
    const float4 e2 = *(const float4*)&esrc[(size_t)(tid + 1024) * 4];
    const float4 e3 = *(const float4*)&esrc[(size_t)(tid + 1536) * 4];

    __syncthreads();  // prior-chunk readers of u_tile/p_lds done
    *(float4*)&u_tile[(rS +  0) * 68 + cgS * 4] = e0;
    *(float4*)&u_tile[(rS + 32) * 68 + cgS * 4] = e1;
    *(float4*)&u_tile[(rS + 64) * 68 + cgS * 4] = e2;
    *(float4*)&u_tile[(rS + 96) * 68 + cgS * 4] = e3;
    __syncthreads();  // e_tile ready

    // ---- phase A: p for 2 heads at j = jc*128 + j_l ----
    {
      const float* er  = &u_tile[j_l * 68];
      const float* qe0 = &s_qe[h0 * EDGE_DIM];
      const float* qe1 = qe0 + EDGE_DIM;
      float s0 = 0.f, s1 = 0.f;
#pragma unroll 4
      for (int c4 = 0; c4 < 16; ++c4) {
        const float4 e4 = *(const float4*)&er[c4 * 4];
        const float4 a0 = *(const float4*)&qe0[c4 * 4];
        const float4 a1 = *(const float4*)&qe1[c4 * 4];
        s0 += e4.x * a0.x + e4.y * a0.y + e4.z * a0.z + e4.w * a0.w;
        s1 += e4.x * a1.x + e4.y * a1.y + e4.z * a1.z + e4.w * a1.w;
      }
      const int jg = jc * 128 + j_l;
      const float qk0 = qkbuf[(size_t)i * (NH * N_NODES) + h0 * N_NODES + jg];
      const float qk1 = qkbuf[(size_t)i * (NH * N_NODES) + (h0 + 1) * N_NODES + jg];
      const float aj = s_adj[jg];
      const float p0 = __expf((s0 + qk0 + s_qb[h0]) * SCALE) * aj;
      const float p1 = __expf((s1 + qk1 + s_qb[h0 + 1]) * SCALE) * aj;
      p_lds[h0 * 128 + j_l]       = p0;
      p_lds[(h0 + 1) * 128 + j_l] = p1;
      hs0 += p0; hs1 += p1;
    }
    __syncthreads();  // p_lds ready

    // ---- phase B: ae accumulation from staged registers ----
#pragma unroll
    for (int h = 0; h < NH; ++h) {
      const float* ph = &p_lds[h * 128 + rS];
      const float pa = ph[0], pb = ph[32], pc = ph[64], pd = ph[96];
      acc4[h].x = fmaf(pa, e0.x, acc4[h].x);
      acc4[h].y = fmaf(pa, e0.y, acc4[h].y);
      acc4[h].z = fmaf(pa, e0.z, acc4[h].z);
      acc4[h].w = fmaf(pa, e0.w, acc4[h].w);
      acc4[h].x = fmaf(pb, e1.x, acc4[h].x);
      acc4[h].y = fmaf(pb, e1.y, acc4[h].y);
      acc4[h].z = fmaf(pb, e1.z, acc4[h].z);
      acc4[h].w = fmaf(pb, e1.w, acc4[h].w);
      acc4[h].x = fmaf(pc, e2.x, acc4[h].x);
      acc4[h].y = fmaf(pc, e2.y, acc4[h].y);
      acc4[h].z = fmaf(pc, e2.z, acc4[h].z);
      acc4[h].w = fmaf(pc, e2.w, acc4[h].w);
      acc4[h].x = fmaf(pd, e3.x, acc4[h].x);
      acc4[h].y = fmaf(pd, e3.y, acc4[h].y);
      acc4[h].z = fmaf(pd, e3.z, acc4[h].z);
      acc4[h].w = fmaf(pd, e3.w, acc4[h].w);
    }

    // ---- phase C: accv (scalar) over 64 j for column nC ----
    {
      const float* vc = v + (size_t)(jc * 128 + p2 * 64) * INNER + nC;
      const float* pr = &p_lds[hv * 128 + p2 * 64];
#pragma unroll 4
      for (int jj4 = 0; jj4 < 16; ++jj4) {
        const float4 p4 = *(const float4*)&pr[jj4 * 4];
        accv = fmaf(p4.x, vc[(size_t)(jj4 * 4 + 0) * INNER], accv);
        accv = fmaf(p4.y, vc[(size_t)(jj4 * 4 + 1) * INNER], accv);
        accv = fmaf(p4.z, vc[(size_t)(jj4 * 4 + 2) * INNER], accv);
        accv = fmaf(p4.w, vc[(size_t)(jj4 * 4 + 3) * INNER], accv);
      }
    }
  }

  // ---- reduce ae across the 4 r's within each wave; publish per-wave ----
  // (u_tile is dead: all waves are past the last p_lds-ready barrier.)
#pragma unroll
  for (int h = 0; h < NH; ++h) {
    acc4[h].x += __shfl_xor(acc4[h].x, 16, 64);
    acc4[h].y += __shfl_xor(acc4[h].y, 16, 64);
    acc4[h].z += __shfl_xor(acc4[h].z, 16, 64);
    acc4[h].w += __shfl_xor(acc4[h].w, 16, 64);
    acc4[h].x += __shfl_xor(acc4[h].x, 32, 64);
    acc4[h].y += __shfl_xor(acc4[h].y, 32, 64);
    acc4[h].z += __shfl_xor(acc4[h].z, 32, 64);
    acc4[h].w += __shfl_xor(acc4[h].w, 32, 64);
  }
  {
    const int wv = tid >> 6;
    if ((tid & 63) < 16) {
#pragma unroll
      for (int h = 0; h < NH; ++h)
        *(float4*)&u_tile[wv * 512 + h * EDGE_DIM + cgS * 4] = acc4[h];
    }
  }

  // ---- hsum reduction + av publish ----
  {
    float a = hs0, b = hs1;
#pragma unroll
    for (int off = 32; off > 0; off >>= 1) {
      a += __shfl_xor(a, off, 64);
      b += __shfl_xor(b, off, 64);
    }
    if ((tid & 63) == 0) { s_hred[tid >> 6][0] = a; s_hred[tid >> 6][1] = b; }
  }
  s_avp[p2][nC] = accv;
  __syncthreads();
  if (tid < NH) {
    const int g = tid >> 1, r = tid & 1;
    const float t = s_hred[g * 2][r] + s_hred[g * 2 + 1][r];
    s_rd[tid] = (t == 0.f) ? 1.f : (1.f / t);
    s_as[tid] = (t == 0.f) ? 0.f : 1.f;
  }
  __syncthreads();

  // ---- combine ae wave-partials, normalize; store at u_tile[4096+tid] ----
  {
    float t = 0.f;
#pragma unroll
    for (int w = 0; w < 8; ++w) t += u_tile[w * 512 + tid];
    u_tile[4096 + tid] = t * s_rd[tid >> 6];
  }
  __syncthreads();

  // ---- epilogue ----
  if (tid < INNER) {
    const int n = tid, h = n >> 5;
    float o = (s_avp[0][n] + s_avp[1][n]) * s_rd[h] + s_as[h] * be[n];
    const float* aeh = &u_tile[4096 + h * EDGE_DIM];
#pragma unroll 8
    for (int cc = 0; cc < EDGE_DIM; ++cc)
      o = fmaf(aeh[cc], We[(size_t)cc * INNER + n], o);
    out[(size_t)i * INNER + n] = o;
  }
}

extern "C" void kernel_launch(void* const* d_in, const int* in_sizes, int n_in,
                              void* d_out, int out_size, void* d_ws, size_t ws_size,
                              hipStream_t stream) {
  const float* nodes     = (const float*)d_in[0];
  const float* edges     = (const float*)d_in[1];
  const int*   adjacency = (const int*)d_in[2];
  const float* Wq = (const float*)d_in[3];
  const float* bq = (const float*)d_in[4];
  const float* Wk = (const float*)d_in[5];
  const float* bk = (const float*)d_in[6];
  const float* Wv = (const float*)d_in[7];
  const float* bv = (const float*)d_in[8];
  const float* We = (const float*)d_in[9];
  const float* be = (const float*)d_in[10];

  float* q   = (float*)d_ws;                           // 512*256
  float* k   = q   + (size_t)N_NODES * INNER;          // 512*256
  float* v   = k   + (size_t)N_NODES * INNER;          // 512*256
  float* qe  = v   + (size_t)N_NODES * INNER;          // 512*512
  float* qb  = qe  + (size_t)N_NODES * NH * EDGE_DIM;  // 512*8
  float* qkb = qb  + (size_t)N_NODES * NH;             // 512*8*512

  proj_qkv<<<dim3(3 * 64), dim3(256), 0, stream>>>(
      nodes, Wq, bq, Wk, bk, Wv, bv, q, k, v);
  qe_qb<<<dim3(64), dim3(512), 0, stream>>>(q, We, be, qe, qb);
  qk_gemm<<<dim3(1024), dim3(256), 0, stream>>>(q, k, qkb);
  fused_attn<<<dim3(N_NODES), dim3(512), 0, stream>>>(
      edges, adjacency, v, qe, qb, qkb, We, be, (float*)d_out);
}